// Round 2
// baseline (497.800 us; speedup 1.0000x reference)
//
#include <hip/hip_runtime.h>

// PQN soft-quantization: x[32768,1024] f32, c[1024,256] f32 -> out[32768,1024] f32
// D=1024, M=8 subspaces of L=128, K=256 codes, logits scaled by 2*ALPHA=20.
//
// Per-wave fused pipeline, 1 block/CU (128 KB LDS), 8 waves/block (2/SIMD).
// Codebook subspace staged in LDS f16 in two layouts:
//   csA: [code][l']  256 B rows, l-permuted to match the line-perfect x-load
//                    k-ordering, XOR-swizzled by (code&15)<<4  (phase-1 A)
//   csB: [l][code]   512 B rows, XOR-swizzled by (l&15)<<4     (phase-2 A)
// Softmax fully in registers. f16 MFMA 16x16x32.

#define D_  1024
#define M_  8
#define K_  256
#define L_  128

typedef _Float16 f16;
typedef f16 f16x8 __attribute__((ext_vector_type(8)));
typedef f16 f16x4 __attribute__((ext_vector_type(4)));
typedef f16 f16x2 __attribute__((ext_vector_type(2)));
typedef float f32x4 __attribute__((ext_vector_type(4)));

__global__ __launch_bounds__(512, 2)
void pqn_kernel(const float* __restrict__ x, const float* __restrict__ c,
                float* __restrict__ out) {
    __shared__ unsigned char lds[131072];
    unsigned char* csA = lds;            // 65536 B : 256 rows x 256 B
    unsigned char* csB = lds + 65536;    // 65536 B : 128 rows x 512 B

    const int tid  = threadIdx.x;
    const int m    = blockIdx.x >> 5;    // 32 blocks per subspace
    const int bm   = blockIdx.x & 31;
    const int lane = tid & 63;
    const int w    = tid >> 6;           // wave 0..7
    const int n    = lane & 15;
    const int g    = lane >> 4;          // quarter-wave
    const int wi   = bm * 8 + w;         // wave index within subspace (0..255)

    // ---- stage codebook subspace m into LDS (f16, both layouts) ----
    const float* cm = c + (size_t)m * L_ * K_;   // cm[l*256 + k]
    #pragma unroll
    for (int itg = 0; itg < 8; ++itg) {
        int idx = itg * 512 + tid;       // 0..4095
        int l   = (idx >> 6) * 2;        // even row 0..126
        int c4  = (idx & 63) << 2;       // code 0..252 step 4
        float4 a = *reinterpret_cast<const float4*>(cm + (size_t)l * K_ + c4);
        float4 b = *reinterpret_cast<const float4*>(cm + (size_t)(l + 1) * K_ + c4);
        f16x4 va = { (f16)a.x, (f16)a.y, (f16)a.z, (f16)a.w };
        f16x4 vb = { (f16)b.x, (f16)b.y, (f16)b.z, (f16)b.w };
        // csB rows l, l+1 (swizzled)
        {
            int off0 = l * 512       + ((c4 * 2) ^ ((l & 15) << 4));
            int off1 = (l + 1) * 512 + ((c4 * 2) ^ (((l + 1) & 15) << 4));
            *reinterpret_cast<f16x4*>(csB + off0) = va;
            *reinterpret_cast<f16x4*>(csB + off1) = vb;
        }
        // csA codes c4..c4+3 at permuted-l positions (l,l+1 stay adjacent)
        {
            int r = l & 31;
            int p = ((r & 15) >> 2) * 8 + ((r >> 4) & 1) * 4 + (r & 3); // even
            int base = (l >> 5) * 64 + 2 * p;   // byte within 256 B row
            #pragma unroll
            for (int j = 0; j < 4; ++j) {
                int code = c4 + j;
                int off = code * 256 + (base ^ ((code & 15) << 4));
                f16x2 t = { va[j], vb[j] };
                *reinterpret_cast<f16x2*>(csA + off) = t;
            }
        }
    }
    __syncthreads();

    // line-perfect x reads: lane(n,g) inst k reads row (r0+n), bytes [k*64+g*16)
    const float* px0 = x + (size_t)m * L_ + g * 4 + (size_t)n * D_;
    float4 xa[8];
    {
        const float* px = px0 + (size_t)(wi * 16) * D_;
        #pragma unroll
        for (int k = 0; k < 8; ++k)
            xa[k] = *reinterpret_cast<const float4*>(px + k * 16);
    }

    for (int it = 0; it < 8; ++it) {
        const int r0 = (it * 256 + wi) * 16;

        // ---- row L2 norm (f32 exact) -> logit scale 20/||x|| ----
        float ss = 0.f;
        #pragma unroll
        for (int k = 0; k < 8; ++k) {
            float4 a = xa[k];
            ss = fmaf(a.x, a.x, ss); ss = fmaf(a.y, a.y, ss);
            ss = fmaf(a.z, a.z, ss); ss = fmaf(a.w, a.w, ss);
        }
        ss += __shfl_xor(ss, 16);
        ss += __shfl_xor(ss, 32);
        const float fac = 20.0f / fmaxf(sqrtf(ss), 1e-12f);

        // ---- B1 fragments: raw x as f16; k-label for elem e is the
        //      permuted l = 32ks + 4g + e (e<4) / 32ks+16+4g+e-4 (e>=4),
        //      matched by csA's stored permutation ----
        f16x8 bf[4];
        #pragma unroll
        for (int ks = 0; ks < 4; ++ks) {
            float4 lo = xa[2 * ks], hi = xa[2 * ks + 1];
            bf[ks][0] = (f16)lo.x; bf[ks][1] = (f16)lo.y;
            bf[ks][2] = (f16)lo.z; bf[ks][3] = (f16)lo.w;
            bf[ks][4] = (f16)hi.x; bf[ks][5] = (f16)hi.y;
            bf[ks][6] = (f16)hi.z; bf[ks][7] = (f16)hi.w;
        }

        // ---- prefetch next row-tile (hidden under compute) ----
        if (it < 7) {
            const float* px = px0 + (size_t)(((it + 1) * 256 + wi) * 16) * D_;
            #pragma unroll
            for (int k = 0; k < 8; ++k)
                xa[k] = *reinterpret_cast<const float4*>(px + k * 16);
        }

        // ---- phase 1: z^T[code][sample] = cs^T . x^T ----
        f32x4 acc[16];
        const f32x4 fzero = {0.f, 0.f, 0.f, 0.f};
        #pragma unroll
        for (int t = 0; t < 16; ++t) acc[t] = fzero;
        #pragma unroll
        for (int ks = 0; ks < 4; ++ks) {
            #pragma unroll
            for (int t = 0; t < 16; ++t) {
                // row code = t*16+n; (code&15)==n
                f16x8 af = *reinterpret_cast<const f16x8*>(
                    csA + (t * 16 + n) * 256 + ((ks * 64 + g * 16) ^ (n << 4)));
                acc[t] = __builtin_amdgcn_mfma_f32_16x16x32_f16(af, bf[ks], acc[t], 0, 0, 0);
            }
        }

        // ---- scale + in-register softmax over 256 codes ----
        float zmax = -3.0e38f;
        #pragma unroll
        for (int t = 0; t < 16; ++t) {
            #pragma unroll
            for (int r = 0; r < 4; ++r) {
                acc[t][r] *= fac;
                zmax = fmaxf(zmax, acc[t][r]);
            }
        }
        zmax = fmaxf(zmax, __shfl_xor(zmax, 16));
        zmax = fmaxf(zmax, __shfl_xor(zmax, 32));
        float S = 0.f;
        #pragma unroll
        for (int t = 0; t < 16; ++t) {
            #pragma unroll
            for (int r = 0; r < 4; ++r) {
                float p = __expf(acc[t][r] - zmax);
                acc[t][r] = p;           // unnormalized; 1/S applied at store
                S += p;
            }
        }
        S += __shfl_xor(S, 16);
        S += __shfl_xor(S, 32);
        const float invS = 1.0f / S;

        // ---- phase 2: out^T[l][sample] = cs . w^T ----
        f32x4 acc2[8];
        #pragma unroll
        for (int t = 0; t < 8; ++t) acc2[t] = fzero;
        #pragma unroll
        for (int ks2 = 0; ks2 < 8; ++ks2) {
            // pb elem i: p(code = ks2*32 + g*8 + i, sample n), pulled from acc
            f16x8 pb;
            #pragma unroll
            for (int i = 0; i < 8; ++i) {
                const int src = (2 * (g & 1) + (i >> 2)) * 16 + n;
                float v0 = __shfl(acc[2 * ks2][i & 3], src);
                float v1 = __shfl(acc[2 * ks2 + 1][i & 3], src);
                pb[i] = (f16)((g < 2) ? v0 : v1);
            }
            #pragma unroll
            for (int nt = 0; nt < 8; ++nt) {
                // row l = nt*16+n; (l&15)==n
                f16x8 a2 = *reinterpret_cast<const f16x8*>(
                    csB + (nt * 16 + n) * 512 + ((ks2 * 64 + g * 16) ^ (n << 4)));
                acc2[nt] = __builtin_amdgcn_mfma_f32_16x16x32_f16(a2, pb, acc2[nt], 0, 0, 0);
            }
        }

        // ---- store: 4 lanes (g=0..3) cover a full 64 B line per row ----
        float* po = out + (size_t)(r0 + n) * D_ + m * L_;
        #pragma unroll
        for (int nt = 0; nt < 8; ++nt) {
            f32x4 v;
            #pragma unroll
            for (int r = 0; r < 4; ++r) v[r] = acc2[nt][r] * invS;
            __builtin_nontemporal_store(v, reinterpret_cast<f32x4*>(po + nt * 16 + g * 4));
        }
    }
}

extern "C" void kernel_launch(void* const* d_in, const int* in_sizes, int n_in,
                              void* d_out, int out_size, void* d_ws, size_t ws_size,
                              hipStream_t stream) {
    const float* x = (const float*)d_in[0];   // [32768, 1024] f32
    const float* c = (const float*)d_in[1];   // [1024, 256]   f32
    float* out = (float*)d_out;               // [32768, 1024] f32
    (void)in_sizes; (void)n_in; (void)out_size; (void)d_ws; (void)ws_size;

    pqn_kernel<<<dim3(256), dim3(512), 0, stream>>>(x, c, out);
}

// Round 4
// 203.965 us; speedup vs baseline: 2.4406x; 2.4406x over previous
//
#include <hip/hip_runtime.h>

// PQN soft-quantization: x[32768,1024] f32, c[1024,256] f32 -> out[32768,1024] f32
// D=1024, M=8 subspaces of L=128, K=256 codes, logits scaled by 2*ALPHA=20.
//
// 32x32x16 f16 MFMA pipeline. One block per CU (128 KB LDS), 8 waves, 2/SIMD.
// Each wave-iter handles 32 samples:
//   phase 1: z^T[256 codes][32 samples] = cs^T . x^T   (A from LDS csA, B = x in regs)
//   softmax: per-lane (each lane owns 1 sample's 128 codes) + one xor-32 shuffle
//   phase 2: out^T[128 l][32 samples] = cs . w^T       (A from LDS csB, B = packed w)
// P-transpose for phase 2 = 2 x v_permlane32_swap per k-step (no LDS, no bpermute).

#define D_  1024
#define K_  256
#define L_  128

typedef _Float16 f16;
typedef f16 f16x8 __attribute__((ext_vector_type(8)));
typedef f16 f16x4 __attribute__((ext_vector_type(4)));
typedef f16 f16x2 __attribute__((ext_vector_type(2)));
typedef float f32x4  __attribute__((ext_vector_type(4)));
typedef float f32x16 __attribute__((ext_vector_type(16)));
typedef unsigned int u32;

__global__ __launch_bounds__(512)
void pqn_kernel(const float* __restrict__ x, const float* __restrict__ c,
                float* __restrict__ out) {
    __shared__ unsigned char lds[131072];
    unsigned char* csA = lds;          // [256 codes][128 l] f16, 256 B rows, swz ^=(code&7)<<4
    unsigned char* csB = lds + 65536;  // [128 l][256 codes] f16, 512 B rows, swz ^=(l&7)<<4

    const int tid  = threadIdx.x;
    const int m    = blockIdx.x >> 5;   // 8 subspaces
    const int bm   = blockIdx.x & 31;   // 32 blocks per subspace
    const int lane = tid & 63;
    const int w    = tid >> 6;          // wave 0..7
    const int n32  = lane & 31;         // sample column
    const int h    = lane >> 5;         // half-wave

    // ---------------- stage codebook subspace m into LDS (f16, both layouts) -------------
    const float* cm = c + (size_t)m * L_ * K_;      // cm[l*256 + k]
    {
        const int R0 = tid >> 6;        // 0..7
        const int f  = tid & 63;        // code quad index
        #pragma unroll
        for (int b = 0; b < 8; ++b) {
            int R  = b * 8 + R0;        // 0..63
            int l0 = 2 * R;             // even row
            float4 a  = *reinterpret_cast<const float4*>(cm + (size_t)l0 * K_ + 4 * f);
            float4 bb = *reinterpret_cast<const float4*>(cm + (size_t)(l0 + 1) * K_ + 4 * f);
            f16x4 va = {(f16)a.x, (f16)a.y, (f16)a.z, (f16)a.w};
            f16x4 vb = {(f16)bb.x, (f16)bb.y, (f16)bb.z, (f16)bb.w};
            *reinterpret_cast<f16x4*>(csB + l0 * 512       + ((8 * f) ^ ((l0 & 7) << 4))) = va;
            *reinterpret_cast<f16x4*>(csB + (l0 + 1) * 512 + ((8 * f) ^ (((l0 + 1) & 7) << 4))) = vb;
            #pragma unroll
            for (int j = 0; j < 4; ++j) {
                int code = 4 * f + j;
                f16x2 t = { va[j], vb[j] };   // elements l0, l0+1 of row `code`
                *reinterpret_cast<f16x2*>(csA + code * 256 + ((4 * R) ^ ((code & 7) << 4))) = t;
            }
        }
    }
    __syncthreads();

    // x fragment loads: lane (n32,h) holds row (r0+n32), floats h*8 + 16k + {0..7}
    const float* xbase = x + (size_t)(bm * 1024 + w * 32 + n32) * D_ + m * L_ + h * 8;
    float4 xa[16];
    {
        const float* p = xbase;
        #pragma unroll
        for (int k = 0; k < 8; ++k) {
            xa[2 * k]     = *reinterpret_cast<const float4*>(p + k * 16);
            xa[2 * k + 1] = *reinterpret_cast<const float4*>(p + k * 16 + 4);
        }
    }

    for (int it = 0; it < 4; ++it) {
        const int r0 = bm * 1024 + it * 256 + w * 32;

        // ---- norm partial (this lane's 64 floats of its row) + B1 fragments ----
        float ss = 0.f;
        f16x8 bf[8];
        #pragma unroll
        for (int k = 0; k < 8; ++k) {
            float4 lo = xa[2 * k], hi = xa[2 * k + 1];
            ss = fmaf(lo.x, lo.x, ss); ss = fmaf(lo.y, lo.y, ss);
            ss = fmaf(lo.z, lo.z, ss); ss = fmaf(lo.w, lo.w, ss);
            ss = fmaf(hi.x, hi.x, ss); ss = fmaf(hi.y, hi.y, ss);
            ss = fmaf(hi.z, hi.z, ss); ss = fmaf(hi.w, hi.w, ss);
            bf[k][0] = (f16)lo.x; bf[k][1] = (f16)lo.y;
            bf[k][2] = (f16)lo.z; bf[k][3] = (f16)lo.w;
            bf[k][4] = (f16)hi.x; bf[k][5] = (f16)hi.y;
            bf[k][6] = (f16)hi.z; bf[k][7] = (f16)hi.w;
        }
        ss += __shfl_xor(ss, 32);                       // full-row sum of squares
        const float fac = 20.0f / fmaxf(sqrtf(ss), 1e-12f);

        // ---- phase 1: acc[ct] = z^T[ct*32+row32][n32], row32=(r&3)+8(r>>2)+4h ----
        f32x16 acc[8];
        #pragma unroll
        for (int ct = 0; ct < 8; ++ct) acc[ct] = (f32x16)(0.f);
        #pragma unroll
        for (int ks = 0; ks < 8; ++ks) {
            #pragma unroll
            for (int ct = 0; ct < 8; ++ct) {
                f16x8 af = *reinterpret_cast<const f16x8*>(
                    csA + (ct * 32 + n32) * 256 + ((ks * 32 + h * 16) ^ ((n32 & 7) << 4)));
                acc[ct] = __builtin_amdgcn_mfma_f32_32x32x16_f16(af, bf[ks], acc[ct], 0, 0, 0);
            }
        }

        // ---- prefetch next iter's x (hidden under softmax + phase 2) ----
        if (it < 3) {
            const float* p = xbase + (size_t)(it + 1) * 256 * D_;
            #pragma unroll
            for (int k = 0; k < 8; ++k) {
                xa[2 * k]     = *reinterpret_cast<const float4*>(p + k * 16);
                xa[2 * k + 1] = *reinterpret_cast<const float4*>(p + k * 16 + 4);
            }
        }

        // ---- softmax over 256 codes: each lane owns sample n32's 128 codes ----
        float z0 = -3.0e38f, z1 = -3.0e38f, z2 = -3.0e38f, z3 = -3.0e38f;
        #pragma unroll
        for (int ct = 0; ct < 8; ++ct) {
            #pragma unroll
            for (int e = 0; e < 4; ++e) {
                z0 = fmaxf(z0, acc[ct][4 * e + 0]);
                z1 = fmaxf(z1, acc[ct][4 * e + 1]);
                z2 = fmaxf(z2, acc[ct][4 * e + 2]);
                z3 = fmaxf(z3, acc[ct][4 * e + 3]);
            }
        }
        float zm = fmaxf(fmaxf(z0, z1), fmaxf(z2, z3));
        zm = fmaxf(zm, __shfl_xor(zm, 32));             // other half of codes
        const float nfz = -fac * zm;

        float s0 = 0.f, s1 = 0.f, s2 = 0.f, s3 = 0.f;
        #pragma unroll
        for (int ct = 0; ct < 8; ++ct) {
            #pragma unroll
            for (int e = 0; e < 4; ++e) {
                float p0 = __expf(fmaf(acc[ct][4 * e + 0], fac, nfz));
                float p1 = __expf(fmaf(acc[ct][4 * e + 1], fac, nfz));
                float p2 = __expf(fmaf(acc[ct][4 * e + 2], fac, nfz));
                float p3 = __expf(fmaf(acc[ct][4 * e + 3], fac, nfz));
                acc[ct][4 * e + 0] = p0; acc[ct][4 * e + 1] = p1;
                acc[ct][4 * e + 2] = p2; acc[ct][4 * e + 3] = p3;
                s0 += p0; s1 += p1; s2 += p2; s3 += p3;
            }
        }
        float S = (s0 + s1) + (s2 + s3);
        S += __shfl_xor(S, 32);
        const float invS = 1.0f / S;

        // ---- pack unnormalized weights to f16 pairs: P[ct][e] = (p[2e], p[2e+1]) ----
        u32 P[8][8];
        #pragma unroll
        for (int ct = 0; ct < 8; ++ct) {
            #pragma unroll
            for (int e = 0; e < 8; ++e) {
                P[ct][e] = __builtin_bit_cast(
                    u32, __builtin_amdgcn_cvt_pkrtz(acc[ct][2 * e], acc[ct][2 * e + 1]));
            }
        }

        // ---- phase 2: out^T[l][n32] = cs . w^T ----
        f32x16 acc2[4];
        #pragma unroll
        for (int lt = 0; lt < 4; ++lt) acc2[lt] = (f32x16)(0.f);
        #pragma unroll
        for (int ks16 = 0; ks16 < 16; ++ks16) {
            const int ct = ks16 >> 1;
            const int eb = 4 * (ks16 & 1);
            // build B fragment: pb[i] = w[ks16*16 + h*8 + i][n32]
            u32 a0 = P[ct][eb + 0], b0 = P[ct][eb + 2];
            u32 a1 = P[ct][eb + 1], b1 = P[ct][eb + 3];
            asm("v_permlane32_swap_b32 %0, %1" : "+v"(a0), "+v"(b0));
            asm("v_permlane32_swap_b32 %0, %1" : "+v"(a1), "+v"(b1));
            union { f16x8 v; u32 q[4]; } pb;
            pb.q[0] = a0; pb.q[1] = a1; pb.q[2] = b0; pb.q[3] = b1;
            #pragma unroll
            for (int lt = 0; lt < 4; ++lt) {
                f16x8 a2 = *reinterpret_cast<const f16x8*>(
                    csB + (lt * 32 + n32) * 512 + ((ks16 * 32 + h * 16) ^ ((n32 & 7) << 4)));
                acc2[lt] = __builtin_amdgcn_mfma_f32_32x32x16_f16(a2, pb.v, acc2[lt], 0, 0, 0);
            }
        }

        // ---- store: l = lt*32 + 8q + 4h + {0..3}, row r0+n32 ----
        float* po = out + (size_t)(r0 + n32) * D_ + m * L_ + h * 4;
        #pragma unroll
        for (int lt = 0; lt < 4; ++lt) {
            #pragma unroll
            for (int q = 0; q < 4; ++q) {
                f32x4 v;
                v[0] = acc2[lt][4 * q + 0] * invS;
                v[1] = acc2[lt][4 * q + 1] * invS;
                v[2] = acc2[lt][4 * q + 2] * invS;
                v[3] = acc2[lt][4 * q + 3] * invS;
                __builtin_nontemporal_store(v,
                    reinterpret_cast<f32x4*>(po + lt * 32 + 8 * q));
            }
        }
    }
}

extern "C" void kernel_launch(void* const* d_in, const int* in_sizes, int n_in,
                              void* d_out, int out_size, void* d_ws, size_t ws_size,
                              hipStream_t stream) {
    const float* x = (const float*)d_in[0];   // [32768, 1024] f32
    const float* c = (const float*)d_in[1];   // [1024, 256]   f32
    float* out = (float*)d_out;               // [32768, 1024] f32
    (void)in_sizes; (void)n_in; (void)out_size; (void)d_ws; (void)ws_size;

    pqn_kernel<<<dim3(256), dim3(512), 0, stream>>>(x, c, out);
}